// Round 2
// baseline (300.421 us; speedup 1.0000x reference)
//
#include <hip/hip_runtime.h>
#include <hip/hip_bf16.h>
#include <stdint.h>

#define BB 2
#define SS 2048
#define DDIM 1024
#define HH 16
#define DEPTH 64
#define MROWS (BB*SS)   // 4096

typedef short bf16x8 __attribute__((ext_vector_type(8)));
typedef float f32x4 __attribute__((ext_vector_type(4)));

__device__ inline ushort f2bf(float f) {
  union { float f; unsigned u; } v; v.f = f;
  unsigned r = v.u + 0x7fffu + ((v.u >> 16) & 1u);
  return (ushort)(r >> 16);
}

__device__ inline void gload_lds16(const void* g, void* l) {
  __builtin_amdgcn_global_load_lds(
      (const __attribute__((address_space(1))) unsigned*)g,
      (__attribute__((address_space(3))) unsigned*)l,
      16, 0, 0);
}

// ---------------- fp32 -> bf16 convert (vectorized) ----------------
__global__ void cvt_f32_bf16_kernel(const float* __restrict__ in,
                                    ushort* __restrict__ out, int n8) {
  int i = blockIdx.x * blockDim.x + threadIdx.x;
  if (i >= n8) return;
  const float4* p = (const float4*)in + (size_t)i * 2;
  float4 a = p[0], b = p[1];
  ushort tmp[8] = { f2bf(a.x), f2bf(a.y), f2bf(a.z), f2bf(a.w),
                    f2bf(b.x), f2bf(b.y), f2bf(b.z), f2bf(b.w) };
  *(uint4*)(out + (size_t)i * 8) = *(uint4*)tmp;
}

// ---------------- weight transpose + convert: T[n][k] = W[k][n] ----------------
__global__ void wtrans_kernel(const float* __restrict__ W0, const float* __restrict__ W1,
                              const float* __restrict__ W2, const float* __restrict__ W3,
                              ushort* __restrict__ T0, ushort* __restrict__ T1,
                              ushort* __restrict__ T2, ushort* __restrict__ T3) {
  __shared__ float tile[32][33];
  int z = blockIdx.z;
  const float* W = (z == 0) ? W0 : (z == 1) ? W1 : (z == 2) ? W2 : W3;
  ushort* T = (z == 0) ? T0 : (z == 1) ? T1 : (z == 2) ? T2 : T3;
  int tx = threadIdx.x, ty = threadIdx.y;   // 32 x 8
  int n0 = blockIdx.x * 32, k0 = blockIdx.y * 32;
#pragma unroll
  for (int i = 0; i < 4; i++)
    tile[ty + i * 8][tx] = W[(size_t)(k0 + ty + i * 8) * DDIM + n0 + tx];
  __syncthreads();
#pragma unroll
  for (int i = 0; i < 4; i++)
    T[(size_t)(n0 + ty + i * 8) * DDIM + k0 + tx] = f2bf(tile[tx][ty + i * 8]);
}

// ---------------- m97-structure bf16 GEMM: out = A[M][K] * Bt[N][K]^T + bias ----
// MODE 0: f32 row-major [M][N] out
// MODE 1: bf16 per-head  out[bh][s][64]   (Q,K for attention)
// MODE 2: bf16 per-head transposed out[bh][64][s]  (V for attention)
template <int MODE>
__global__ __launch_bounds__(256) void gemm_bt_kernel(
    const ushort* __restrict__ A, const ushort* __restrict__ Bt,
    const float* __restrict__ bias, void* __restrict__ out,
    int M, int N, int K) {
  __shared__ ushort As[128 * 32];
  __shared__ ushort Bs[128 * 32];
  const int tid = threadIdx.x;
  const int w = tid >> 6, lane = tid & 63;
  const int m0 = blockIdx.y * 128, n0 = blockIdx.x * 128;
  const int wr = (w >> 1) * 64, wc = (w & 1) * 64;
  const int l4 = lane >> 4, l15 = lane & 15;
  const int srow = lane >> 2;         // 0..15
  const int scol = (lane & 3) * 8;    // bf16 elements (16B)

  f32x4 zero = {0.f, 0.f, 0.f, 0.f};
  f32x4 acc[4][4];
#pragma unroll
  for (int i = 0; i < 4; i++)
#pragma unroll
    for (int j = 0; j < 4; j++) acc[i][j] = zero;

  for (int k0 = 0; k0 < K; k0 += 32) {
#pragma unroll
    for (int it = 0; it < 2; ++it) {
      int r = it * 64 + w * 16;
      gload_lds16(A + (size_t)(m0 + r + srow) * K + k0 + scol, &As[r * 32]);
      gload_lds16(Bt + (size_t)(n0 + r + srow) * K + k0 + scol, &Bs[r * 32]);
    }
    __syncthreads();
    bf16x8 af[4], bf[4];
#pragma unroll
    for (int m = 0; m < 4; m++)
      af[m] = *(const bf16x8*)&As[(wr + m * 16 + l15) * 32 + l4 * 8];
#pragma unroll
    for (int n = 0; n < 4; n++)
      bf[n] = *(const bf16x8*)&Bs[(wc + n * 16 + l15) * 32 + l4 * 8];
#pragma unroll
    for (int m = 0; m < 4; m++)
#pragma unroll
      for (int n = 0; n < 4; n++)
        acc[m][n] = __builtin_amdgcn_mfma_f32_16x16x32_bf16(af[m], bf[n], acc[m][n], 0, 0, 0);
    __syncthreads();
  }

#pragma unroll
  for (int m = 0; m < 4; m++) {
#pragma unroll
    for (int n = 0; n < 4; n++) {
      int col = n0 + wc + n * 16 + l15;
      float bv = bias[col];
#pragma unroll
      for (int r = 0; r < 4; r++) {
        int row = m0 + wr + m * 16 + l4 * 4 + r;
        float v = acc[m][n][r] + bv;
        if (MODE == 0) {
          ((float*)out)[(size_t)row * N + col] = v;
        } else {
          int hh = col >> 6, dd = col & 63;
          int bb = row >> 11, s = row & (SS - 1);
          size_t addr;
          if (MODE == 1) addr = ((size_t)(bb * HH + hh) * SS + s) * DEPTH + dd;
          else           addr = ((size_t)(bb * HH + hh) * DEPTH + dd) * SS + s;
          ((ushort*)out)[addr] = f2bf(v);
        }
      }
    }
  }
}

// ---------------- causal flash attention, no-barrier, L2-direct K/V ----------------
// Qh,Kh: [bh][2048][64] bf16 ; Vt: [bh][64][2048] bf16 ; ctx: [4096][1024] bf16
__global__ __launch_bounds__(64) void attn_kernel(
    const ushort* __restrict__ Qh, const ushort* __restrict__ Kh,
    const ushort* __restrict__ Vt, ushort* __restrict__ ctx) {
  __shared__ ushort Pw[16 * 72];      // wave-private, padded (2-way = free)
  const int lane = threadIdx.x;
  const int l4 = lane >> 4, l15 = lane & 15;
  const int c = blockIdx.x;          // q-chunk of 16 rows, 0..127
  const int bh = blockIdx.y;         // 0..31
  const int b = bh >> 4, h = bh & 15;
  const size_t qkbase = (size_t)bh * SS * DEPTH;
  const size_t vbase  = (size_t)bh * DEPTH * SS;
  const int q0 = c * 16;

  bf16x8 aq[2];
#pragma unroll
  for (int cc = 0; cc < 2; cc++)
    aq[cc] = *(const bf16x8*)&Qh[qkbase + (size_t)(q0 + l15) * DEPTH + cc * 32 + l4 * 8];

  f32x4 zero = {0.f, 0.f, 0.f, 0.f};
  f32x4 o[4];
  float m_run[4], l_run[4];
#pragma unroll
  for (int d = 0; d < 4; d++) o[d] = zero;
#pragma unroll
  for (int r = 0; r < 4; r++) { m_run[r] = -__builtin_inff(); l_run[r] = 0.f; }

  const int ndiag = q0 >> 6;   // index of diagonal kv tile

  for (int t = 0; t <= ndiag; ++t) {
    const int kv0 = t * 64;

    // S = (Q K^T) * 1/sqrt(64)   — K fragments straight from L2
    f32x4 s[4];
#pragma unroll
    for (int n = 0; n < 4; n++) {
      f32x4 z = zero;
#pragma unroll
      for (int cc = 0; cc < 2; cc++) {
        bf16x8 bk = *(const bf16x8*)&Kh[qkbase + (size_t)(kv0 + n * 16 + l15) * DEPTH + cc * 32 + l4 * 8];
        z = __builtin_amdgcn_mfma_f32_16x16x32_bf16(aq[cc], bk, z, 0, 0, 0);
      }
      s[n] = z * 0.125f;
    }

    // V^T fragments — issue early so latency hides under softmax VALU
    bf16x8 bv[4][2];
#pragma unroll
    for (int d = 0; d < 4; d++)
#pragma unroll
      for (int cc = 0; cc < 2; cc++)
        bv[d][cc] = *(const bf16x8*)&Vt[vbase + (size_t)(d * 16 + l15) * SS + kv0 + cc * 32 + l4 * 8];

    // causal mask — diagonal tile only (wave-uniform branch)
    if (t == ndiag) {
#pragma unroll
      for (int r = 0; r < 4; r++) {
        int qg = q0 + l4 * 4 + r;
#pragma unroll
        for (int n = 0; n < 4; n++)
          if (kv0 + n * 16 + l15 > qg) s[n][r] = -1e9f;
      }
    }

    // online softmax
#pragma unroll
    for (int r = 0; r < 4; r++) {
      float mx = fmaxf(fmaxf(s[0][r], s[1][r]), fmaxf(s[2][r], s[3][r]));
#pragma unroll
      for (int off = 1; off < 16; off <<= 1)
        mx = fmaxf(mx, __shfl_xor(mx, off));
      float mn = fmaxf(m_run[r], mx);
      float alpha = __expf(m_run[r] - mn);
      m_run[r] = mn;
      float rs = 0.f;
#pragma unroll
      for (int n = 0; n < 4; n++) {
        float p0 = __expf(s[n][r] - mn);
        s[n][r] = p0;
        rs += p0;
      }
      l_run[r] = l_run[r] * alpha + rs;
#pragma unroll
      for (int d = 0; d < 4; d++) o[d][r] *= alpha;
    }

    // P -> wave-private LDS (transpose to A-fragment layout)
#pragma unroll
    for (int r = 0; r < 4; r++)
#pragma unroll
      for (int n = 0; n < 4; n++)
        Pw[(l4 * 4 + r) * 72 + n * 16 + l15] = f2bf(s[n][r]);

    bf16x8 pa[2];
#pragma unroll
    for (int cc = 0; cc < 2; cc++)
      pa[cc] = *(const bf16x8*)&Pw[l15 * 72 + cc * 32 + l4 * 8];

    // O += P V
#pragma unroll
    for (int d = 0; d < 4; d++)
#pragma unroll
      for (int cc = 0; cc < 2; cc++)
        o[d] = __builtin_amdgcn_mfma_f32_16x16x32_bf16(pa[cc], bv[d][cc], o[d], 0, 0, 0);
  }

  // finalize: divide by row sum (reduce partial sums across l15 group), write ctx
#pragma unroll
  for (int r = 0; r < 4; r++) {
    float lv = l_run[r];
#pragma unroll
    for (int off = 1; off < 16; off <<= 1) lv += __shfl_xor(lv, off);
    l_run[r] = 1.f / lv;
  }
#pragma unroll
  for (int d = 0; d < 4; d++)
#pragma unroll
    for (int r = 0; r < 4; r++) {
      int row = q0 + l4 * 4 + r;
      ctx[((size_t)(b * SS + row)) * DDIM + h * DEPTH + d * 16 + l15] = f2bf(o[d][r] * l_run[r]);
    }
}

extern "C" void kernel_launch(void* const* d_in, const int* in_sizes, int n_in,
                              void* d_out, int out_size, void* d_ws, size_t ws_size,
                              hipStream_t stream) {
  const float* query = (const float*)d_in[0];
  const float* key_  = (const float*)d_in[1];
  const float* value = (const float*)d_in[2];
  // d_in[3] = mask (causal; computed analytically in-kernel)
  const float* Wq = (const float*)d_in[4];
  const float* Wk = (const float*)d_in[5];
  const float* Wv = (const float*)d_in[6];
  const float* Wo = (const float*)d_in[7];
  const float* bq = (const float*)d_in[8];
  const float* bk = (const float*)d_in[9];
  const float* bv = (const float*)d_in[10];
  const float* bo = (const float*)d_in[11];

  char* ws = (char*)d_ws;
  const size_t MB = 1u << 20;
  ushort* Xq  = (ushort*)(ws + 0 * MB);
  ushort* Xk  = (ushort*)(ws + 8 * MB);
  ushort* Xv  = (ushort*)(ws + 16 * MB);
  ushort* Wqt = (ushort*)(ws + 24 * MB);
  ushort* Wkt = (ushort*)(ws + 26 * MB);
  ushort* Wvt = (ushort*)(ws + 28 * MB);
  ushort* Wot = (ushort*)(ws + 30 * MB);
  ushort* Qh  = (ushort*)(ws + 32 * MB);   // [bh][2048][64]
  ushort* Kh  = (ushort*)(ws + 40 * MB);   // [bh][2048][64]
  ushort* Vtg = (ushort*)(ws + 48 * MB);   // [bh][64][2048]
  ushort* Cb  = (ushort*)(ws + 56 * MB);   // [4096][1024]

  const int n = MROWS * DDIM;           // 4,194,304
  const int n8 = n / 8;                 // 524,288
  cvt_f32_bf16_kernel<<<n8 / 256, 256, 0, stream>>>(query, Xq, n8);
  cvt_f32_bf16_kernel<<<n8 / 256, 256, 0, stream>>>(key_,  Xk, n8);
  cvt_f32_bf16_kernel<<<n8 / 256, 256, 0, stream>>>(value, Xv, n8);
  wtrans_kernel<<<dim3(32, 32, 4), dim3(32, 8), 0, stream>>>(
      Wq, Wk, Wv, Wo, Wqt, Wkt, Wvt, Wot);

  dim3 gg(DDIM / 128, MROWS / 128);     // (8, 32)
  gemm_bt_kernel<1><<<gg, 256, 0, stream>>>(Xq, Wqt, bq, Qh, MROWS, DDIM, DDIM);
  gemm_bt_kernel<1><<<gg, 256, 0, stream>>>(Xk, Wkt, bk, Kh, MROWS, DDIM, DDIM);
  gemm_bt_kernel<2><<<gg, 256, 0, stream>>>(Xv, Wvt, bv, Vtg, MROWS, DDIM, DDIM);

  attn_kernel<<<dim3(SS / 16, BB * HH), 64, 0, stream>>>(Qh, Kh, Vtg, Cb);

  gemm_bt_kernel<0><<<gg, 256, 0, stream>>>(Cb, Wot, bo, (float*)d_out, MROWS, DDIM, DDIM);
}

// Round 3
// 153.302 us; speedup vs baseline: 1.9597x; 1.9597x over previous
//
#include <hip/hip_runtime.h>
#include <hip/hip_bf16.h>
#include <stdint.h>

#define BB 2
#define SS 2048
#define DDIM 1024
#define HH 16
#define DEPTH 64
#define MROWS (BB*SS)   // 4096

typedef short bf16x8 __attribute__((ext_vector_type(8)));
typedef float f32x4 __attribute__((ext_vector_type(4)));

__device__ inline ushort f2bf(float f) {
  union { float f; unsigned u; } v; v.f = f;
  unsigned r = v.u + 0x7fffu + ((v.u >> 16) & 1u);
  return (ushort)(r >> 16);
}

__device__ inline void gload_lds16(const void* g, void* l) {
  __builtin_amdgcn_global_load_lds(
      (const __attribute__((address_space(1))) unsigned*)g,
      (__attribute__((address_space(3))) unsigned*)l,
      16, 0, 0);
}

// ---------------- fp32 -> bf16 convert (3 tensors fused) ----------------
__global__ void cvt3_kernel(const float* __restrict__ q, const float* __restrict__ k,
                            const float* __restrict__ v,
                            ushort* __restrict__ xq, ushort* __restrict__ xk,
                            ushort* __restrict__ xv, int n8) {
  int z = blockIdx.y;
  const float* in = (z == 0) ? q : (z == 1) ? k : v;
  ushort* out = (z == 0) ? xq : (z == 1) ? xk : xv;
  int i = blockIdx.x * blockDim.x + threadIdx.x;
  if (i >= n8) return;
  const float4* p = (const float4*)in + (size_t)i * 2;
  float4 a = p[0], b = p[1];
  ushort tmp[8] = { f2bf(a.x), f2bf(a.y), f2bf(a.z), f2bf(a.w),
                    f2bf(b.x), f2bf(b.y), f2bf(b.z), f2bf(b.w) };
  *(uint4*)(out + (size_t)i * 8) = *(uint4*)tmp;
}

// ---------------- weight transpose + convert: T[n][k] = W[k][n] ----------------
__global__ void wtrans_kernel(const float* __restrict__ W0, const float* __restrict__ W1,
                              const float* __restrict__ W2, const float* __restrict__ W3,
                              ushort* __restrict__ T0, ushort* __restrict__ T1,
                              ushort* __restrict__ T2, ushort* __restrict__ T3) {
  __shared__ float tile[32][33];
  int z = blockIdx.z;
  const float* W = (z == 0) ? W0 : (z == 1) ? W1 : (z == 2) ? W2 : W3;
  ushort* T = (z == 0) ? T0 : (z == 1) ? T1 : (z == 2) ? T2 : T3;
  int tx = threadIdx.x, ty = threadIdx.y;   // 32 x 8
  int n0 = blockIdx.x * 32, k0 = blockIdx.y * 32;
#pragma unroll
  for (int i = 0; i < 4; i++)
    tile[ty + i * 8][tx] = W[(size_t)(k0 + ty + i * 8) * DDIM + n0 + tx];
  __syncthreads();
#pragma unroll
  for (int i = 0; i < 4; i++)
    T[(size_t)(n0 + ty + i * 8) * DDIM + k0 + tx] = f2bf(tile[tx][ty + i * 8]);
}

// ---------------- fused Q/K/V projection GEMM (m97 structure, z selects) ----------
// out z=0: Qh[bh][2048][64], z=1: Kh[bh][2048][64], z=2: Vt[bh][64][2048]
__global__ __launch_bounds__(256) void qkv_gemm_kernel(
    const ushort* __restrict__ Xq, const ushort* __restrict__ Xk, const ushort* __restrict__ Xv,
    const ushort* __restrict__ Wqt, const ushort* __restrict__ Wkt, const ushort* __restrict__ Wvt,
    const float* __restrict__ bqp, const float* __restrict__ bkp, const float* __restrict__ bvp,
    ushort* __restrict__ Qh, ushort* __restrict__ Kh, ushort* __restrict__ Vtg) {
  const int z = blockIdx.z;
  const ushort* A  = (z == 0) ? Xq  : (z == 1) ? Xk  : Xv;
  const ushort* Bt = (z == 0) ? Wqt : (z == 1) ? Wkt : Wvt;
  const float* bias = (z == 0) ? bqp : (z == 1) ? bkp : bvp;
  ushort* outp = (z == 0) ? Qh : (z == 1) ? Kh : Vtg;
  const int K = DDIM, N = DDIM;

  __shared__ __align__(16) ushort As[128 * 32];
  __shared__ __align__(16) ushort Bs[128 * 32];
  const int tid = threadIdx.x;
  const int w = tid >> 6, lane = tid & 63;
  const int m0 = blockIdx.y * 128, n0 = blockIdx.x * 128;
  const int wr = (w >> 1) * 64, wc = (w & 1) * 64;
  const int l4 = lane >> 4, l15 = lane & 15;
  const int srow = lane >> 2;
  const int scol = (lane & 3) * 8;

  f32x4 zero = {0.f, 0.f, 0.f, 0.f};
  f32x4 acc[4][4];
#pragma unroll
  for (int i = 0; i < 4; i++)
#pragma unroll
    for (int j = 0; j < 4; j++) acc[i][j] = zero;

  for (int k0 = 0; k0 < K; k0 += 32) {
#pragma unroll
    for (int it = 0; it < 2; ++it) {
      int r = it * 64 + w * 16;
      gload_lds16(A + (size_t)(m0 + r + srow) * K + k0 + scol, &As[r * 32]);
      gload_lds16(Bt + (size_t)(n0 + r + srow) * K + k0 + scol, &Bs[r * 32]);
    }
    __syncthreads();
    bf16x8 af[4], bfr[4];
#pragma unroll
    for (int m = 0; m < 4; m++)
      af[m] = *(const bf16x8*)&As[(wr + m * 16 + l15) * 32 + l4 * 8];
#pragma unroll
    for (int n = 0; n < 4; n++)
      bfr[n] = *(const bf16x8*)&Bs[(wc + n * 16 + l15) * 32 + l4 * 8];
#pragma unroll
    for (int m = 0; m < 4; m++)
#pragma unroll
      for (int n = 0; n < 4; n++)
        acc[m][n] = __builtin_amdgcn_mfma_f32_16x16x32_bf16(af[m], bfr[n], acc[m][n], 0, 0, 0);
    __syncthreads();
  }

#pragma unroll
  for (int m = 0; m < 4; m++) {
#pragma unroll
    for (int n = 0; n < 4; n++) {
      int col = n0 + wc + n * 16 + l15;
      float bv = bias[col];
      int hh = col >> 6, dd = col & 63;
#pragma unroll
      for (int r = 0; r < 4; r++) {
        int row = m0 + wr + m * 16 + l4 * 4 + r;
        float v = acc[m][n][r] + bv;
        int bb = row >> 11, s = row & (SS - 1);
        size_t addr = (z == 2)
            ? ((size_t)(bb * HH + hh) * DEPTH + dd) * SS + s
            : ((size_t)(bb * HH + hh) * SS + s) * DEPTH + dd;
        outp[addr] = f2bf(v);
      }
    }
  }
}

// ---------------- output GEMM: out = A[M][K] * Bt[N][K]^T + bias (f32 out) ------
__global__ __launch_bounds__(256) void out_gemm_kernel(
    const ushort* __restrict__ A, const ushort* __restrict__ Bt,
    const float* __restrict__ bias, float* __restrict__ out,
    int M, int N, int K) {
  __shared__ __align__(16) ushort As[128 * 32];
  __shared__ __align__(16) ushort Bs[128 * 32];
  const int tid = threadIdx.x;
  const int w = tid >> 6, lane = tid & 63;
  const int m0 = blockIdx.y * 128, n0 = blockIdx.x * 128;
  const int wr = (w >> 1) * 64, wc = (w & 1) * 64;
  const int l4 = lane >> 4, l15 = lane & 15;
  const int srow = lane >> 2;
  const int scol = (lane & 3) * 8;

  f32x4 zero = {0.f, 0.f, 0.f, 0.f};
  f32x4 acc[4][4];
#pragma unroll
  for (int i = 0; i < 4; i++)
#pragma unroll
    for (int j = 0; j < 4; j++) acc[i][j] = zero;

  for (int k0 = 0; k0 < K; k0 += 32) {
#pragma unroll
    for (int it = 0; it < 2; ++it) {
      int r = it * 64 + w * 16;
      gload_lds16(A + (size_t)(m0 + r + srow) * K + k0 + scol, &As[r * 32]);
      gload_lds16(Bt + (size_t)(n0 + r + srow) * K + k0 + scol, &Bs[r * 32]);
    }
    __syncthreads();
    bf16x8 af[4], bfr[4];
#pragma unroll
    for (int m = 0; m < 4; m++)
      af[m] = *(const bf16x8*)&As[(wr + m * 16 + l15) * 32 + l4 * 8];
#pragma unroll
    for (int n = 0; n < 4; n++)
      bfr[n] = *(const bf16x8*)&Bs[(wc + n * 16 + l15) * 32 + l4 * 8];
#pragma unroll
    for (int m = 0; m < 4; m++)
#pragma unroll
      for (int n = 0; n < 4; n++)
        acc[m][n] = __builtin_amdgcn_mfma_f32_16x16x32_bf16(af[m], bfr[n], acc[m][n], 0, 0, 0);
    __syncthreads();
  }

#pragma unroll
  for (int m = 0; m < 4; m++) {
#pragma unroll
    for (int n = 0; n < 4; n++) {
      int col = n0 + wc + n * 16 + l15;
      float bv = bias[col];
#pragma unroll
      for (int r = 0; r < 4; r++) {
        int row = m0 + wr + m * 16 + l4 * 4 + r;
        out[(size_t)row * N + col] = acc[m][n][r] + bv;
      }
    }
  }
}

// ---------------- causal flash attention: 4 waves, swizzled LDS dbuf staging -----
// Qh,Kh: [bh][2048][64] bf16 ; Vt: [bh][64][2048] bf16 ; ctx: [4096][1024] bf16
// Block = pair of q-chunks (c, 31-c), 64 rows each -> 33 tiles/block balanced.
__global__ __launch_bounds__(256) void attn_kernel(
    const ushort* __restrict__ Qh, const ushort* __restrict__ Kh,
    const ushort* __restrict__ Vt, ushort* __restrict__ ctx) {
  __shared__ __align__(16) ushort Ks[2][64 * 64];   // [kv][d], XOR-swizzled
  __shared__ __align__(16) ushort Vs[2][64 * 64];   // [d][kv], XOR-swizzled
  __shared__ __align__(16) ushort Ps[4][16 * 72];   // per-wave P transpose, padded
  const int tid = threadIdx.x;
  const int w = tid >> 6, lane = tid & 63;
  const int l4 = lane >> 4, l15 = lane & 15;

  // bijective XCD swizzle: 512 blocks, 64 per XCD -> 4 heads per XCD
  int linear = blockIdx.x + blockIdx.y * 16;        // gridDim = (16, 32)
  int serial = (linear & 7) * 64 + (linear >> 3);
  const int qpair = serial & 15;                    // 0..15
  const int bh = serial >> 4;                       // 0..31
  const int b = bh >> 4, h = bh & 15;
  const size_t qkbase = (size_t)bh * SS * DEPTH;
  const size_t vbase  = (size_t)bh * DEPTH * SS;

  // staging geometry: per it, wave covers rows [it*32 + w*8 + lane/8], 16B col chunk
  const int srow_w = w * 8 + (lane >> 3);
  const int colb_lin = (lane & 7) * 16;             // linear byte col within 128B row
  const int swz_rd = (l15 & 7) << 3;                // element XOR for frag reads

  for (int pass = 0; pass < 2; ++pass) {
    const int chunk = pass ? (31 - qpair) : qpair;
    const int q0 = chunk * 64 + w * 16;
    const int nt = chunk + 1;

    bf16x8 aq[2];
#pragma unroll
    for (int cc = 0; cc < 2; cc++)
      aq[cc] = *(const bf16x8*)&Qh[qkbase + (size_t)(q0 + l15) * DEPTH + cc * 32 + l4 * 8];

    f32x4 zero = {0.f, 0.f, 0.f, 0.f};
    f32x4 o[4];
    float m_run[4], l_run[4];
#pragma unroll
    for (int d = 0; d < 4; d++) o[d] = zero;
#pragma unroll
    for (int r = 0; r < 4; r++) { m_run[r] = -__builtin_inff(); l_run[r] = 0.f; }

    // ---- prologue: stage tile 0 into buf 0 ----
    int buf = 0;
#pragma unroll
    for (int it = 0; it < 2; ++it) {
      int row = it * 32 + srow_w;
      int colb = colb_lin ^ ((row & 7) << 4);
      int col_e = colb >> 1;
      int ldsoff = it * 2048 + w * 512;             // ushort units
      gload_lds16(Kh + qkbase + (size_t)row * DEPTH + col_e, &Ks[0][ldsoff]);
      gload_lds16(Vt + vbase + (size_t)row * SS + col_e, &Vs[0][ldsoff]);
    }
    __syncthreads();

    for (int t = 0; t < nt; ++t) {
      // ---- stage tile t+1 into buf^1 (in flight across compute) ----
      if (t + 1 < nt) {
        const int kv1 = (t + 1) * 64;
#pragma unroll
        for (int it = 0; it < 2; ++it) {
          int row = it * 32 + srow_w;
          int colb = colb_lin ^ ((row & 7) << 4);
          int col_e = colb >> 1;
          int ldsoff = it * 2048 + w * 512;
          gload_lds16(Kh + qkbase + (size_t)(kv1 + row) * DEPTH + col_e, &Ks[buf ^ 1][ldsoff]);
          gload_lds16(Vt + vbase + (size_t)row * SS + kv1 + col_e, &Vs[buf ^ 1][ldsoff]);
        }
      }

      const int kv0 = t * 64;
      // ---- S = (Q K^T) * 1/sqrt(64) ----
      f32x4 s[4];
#pragma unroll
      for (int n = 0; n < 4; n++) {
        f32x4 zacc = zero;
        int kr = n * 16 + l15;
#pragma unroll
        for (int cc = 0; cc < 2; cc++) {
          bf16x8 bk = *(const bf16x8*)&Ks[buf][kr * 64 + ((cc * 32 + l4 * 8) ^ swz_rd)];
          zacc = __builtin_amdgcn_mfma_f32_16x16x32_bf16(aq[cc], bk, zacc, 0, 0, 0);
        }
        s[n] = zacc * 0.125f;
      }

      // ---- causal mask on diagonal tile ----
      if (t == nt - 1) {
#pragma unroll
        for (int r = 0; r < 4; r++) {
          int qg = q0 + l4 * 4 + r;
#pragma unroll
          for (int n = 0; n < 4; n++)
            if (kv0 + n * 16 + l15 > qg) s[n][r] = -1e9f;
        }
      }

      // ---- online softmax ----
#pragma unroll
      for (int r = 0; r < 4; r++) {
        float mx = fmaxf(fmaxf(s[0][r], s[1][r]), fmaxf(s[2][r], s[3][r]));
#pragma unroll
        for (int off = 1; off < 16; off <<= 1)
          mx = fmaxf(mx, __shfl_xor(mx, off));
        float mn = fmaxf(m_run[r], mx);
        float alpha = __expf(m_run[r] - mn);
        m_run[r] = mn;
        float rs = 0.f;
#pragma unroll
        for (int n = 0; n < 4; n++) {
          float p0 = __expf(s[n][r] - mn);
          s[n][r] = p0;
          rs += p0;
        }
        l_run[r] = l_run[r] * alpha + rs;
#pragma unroll
        for (int d = 0; d < 4; d++) o[d][r] *= alpha;
      }

      // ---- P -> wave-private LDS (transpose to A-frag layout) ----
      ushort* Pw = &Ps[w][0];
#pragma unroll
      for (int r = 0; r < 4; r++)
#pragma unroll
        for (int n = 0; n < 4; n++)
          Pw[(l4 * 4 + r) * 72 + n * 16 + l15] = f2bf(s[n][r]);

      bf16x8 pa[2];
#pragma unroll
      for (int cc = 0; cc < 2; cc++)
        pa[cc] = *(const bf16x8*)&Pw[l15 * 72 + cc * 32 + l4 * 8];

      // ---- O += P V ----
#pragma unroll
      for (int d = 0; d < 4; d++) {
        int dr = d * 16 + l15;
#pragma unroll
        for (int cc = 0; cc < 2; cc++) {
          bf16x8 bv = *(const bf16x8*)&Vs[buf][dr * 64 + ((cc * 32 + l4 * 8) ^ swz_rd)];
          o[d] = __builtin_amdgcn_mfma_f32_16x16x32_bf16(pa[cc], bv, o[d], 0, 0, 0);
        }
      }

      __syncthreads();     // drains vmcnt (staged tile t+1 landed) + LDS reads done
      buf ^= 1;
    }

    // ---- finalize & write ctx ----
#pragma unroll
    for (int r = 0; r < 4; r++) {
      float lv = l_run[r];
#pragma unroll
      for (int off = 1; off < 16; off <<= 1) lv += __shfl_xor(lv, off);
      l_run[r] = 1.f / lv;
    }
#pragma unroll
    for (int d = 0; d < 4; d++)
#pragma unroll
      for (int r = 0; r < 4; r++) {
        int row = q0 + l4 * 4 + r;
        ctx[((size_t)(b * SS + row)) * DDIM + h * DEPTH + d * 16 + l15] = f2bf(o[d][r] * l_run[r]);
      }
  }
}

extern "C" void kernel_launch(void* const* d_in, const int* in_sizes, int n_in,
                              void* d_out, int out_size, void* d_ws, size_t ws_size,
                              hipStream_t stream) {
  const float* query = (const float*)d_in[0];
  const float* key_  = (const float*)d_in[1];
  const float* value = (const float*)d_in[2];
  // d_in[3] = mask (causal; computed analytically in-kernel)
  const float* Wq = (const float*)d_in[4];
  const float* Wk = (const float*)d_in[5];
  const float* Wv = (const float*)d_in[6];
  const float* Wo = (const float*)d_in[7];
  const float* bq = (const float*)d_in[8];
  const float* bk = (const float*)d_in[9];
  const float* bv = (const float*)d_in[10];
  const float* bo = (const float*)d_in[11];

  char* ws = (char*)d_ws;
  const size_t MB = 1u << 20;
  ushort* Xq  = (ushort*)(ws + 0 * MB);
  ushort* Xk  = (ushort*)(ws + 8 * MB);
  ushort* Xv  = (ushort*)(ws + 16 * MB);
  ushort* Wqt = (ushort*)(ws + 24 * MB);
  ushort* Wkt = (ushort*)(ws + 26 * MB);
  ushort* Wvt = (ushort*)(ws + 28 * MB);
  ushort* Wot = (ushort*)(ws + 30 * MB);
  ushort* Qh  = (ushort*)(ws + 32 * MB);   // [bh][2048][64]
  ushort* Kh  = (ushort*)(ws + 40 * MB);   // [bh][2048][64]
  ushort* Vtg = (ushort*)(ws + 48 * MB);   // [bh][64][2048]
  ushort* Cb  = (ushort*)(ws + 56 * MB);   // [4096][1024]

  const int n = MROWS * DDIM;           // 4,194,304
  const int n8 = n / 8;                 // 524,288
  cvt3_kernel<<<dim3(n8 / 256, 3), 256, 0, stream>>>(query, key_, value, Xq, Xk, Xv, n8);
  wtrans_kernel<<<dim3(32, 32, 4), dim3(32, 8), 0, stream>>>(
      Wq, Wk, Wv, Wo, Wqt, Wkt, Wvt, Wot);

  qkv_gemm_kernel<<<dim3(DDIM / 128, MROWS / 128, 3), 256, 0, stream>>>(
      Xq, Xk, Xv, Wqt, Wkt, Wvt, bq, bk, bv, Qh, Kh, Vtg);

  attn_kernel<<<dim3(16, 32), 256, 0, stream>>>(Qh, Kh, Vtg, Cb);

  out_gemm_kernel<<<dim3(DDIM / 128, MROWS / 128), 256, 0, stream>>>(
      Cb, Wot, bo, (float*)d_out, MROWS, DDIM, DDIM);
}